// Round 6
// baseline (184.556 us; speedup 1.0000x reference)
//
#include <hip/hip_runtime.h>
#include <hip/hip_bf16.h>

// One-hot: label (H*W int32) -> out (N, H, W) float32.
// Ideal traffic = 64 MiB read + 512 MiB write.
//
// Journal:
//  R1 (8 plane-streams/thread, read-once):   130 us = 4.63 TB/s (8 concurrent 64MiB-apart write windows are slow)
//  R3 (nontemporal stores):                  250 us (nt bypasses L2 write-combine -> partial-line RMW; never again)
//  R4 (plane per blockIdx.y, 1 write window):146 us (writes fast, but 64MiB int32 label re-fetch thrashed L3)
//  R5 (wave-per-plane, staggered):           153 us (still 8 concurrent 64MiB-apart windows)
//
// R6: two kernels. k1 packs int32 labels -> uint8 (16 MiB) in d_ws.
//     k2 = R4 structure (one plane per blockIdx.y, single contiguous
//     concurrent write window = fillBuffer-class BW) but reads the 16 MiB
//     packed label, which stays L3-resident across all 8 plane passes.

typedef unsigned int u32;

// k1: pack 16 labels/thread: 4x int4 in -> 16 bytes (uint4) out.
__global__ void __launch_bounds__(256) pack_labels_kernel(
    const int* __restrict__ label, u32* __restrict__ packed, int total) {
    int t = blockIdx.x * 256 + threadIdx.x;
    long long i = (long long)t * 16;
    if (i >= total) return;
    const int4* lp = reinterpret_cast<const int4*>(label + i);
    int4 a = lp[0], b = lp[1], c = lp[2], d = lp[3];
    u32 p0 = (u32)(a.x & 255) | ((u32)(a.y & 255) << 8) | ((u32)(a.z & 255) << 16) | ((u32)(a.w & 255) << 24);
    u32 p1 = (u32)(b.x & 255) | ((u32)(b.y & 255) << 8) | ((u32)(b.z & 255) << 16) | ((u32)(b.w & 255) << 24);
    u32 p2 = (u32)(c.x & 255) | ((u32)(c.y & 255) << 8) | ((u32)(c.z & 255) << 16) | ((u32)(c.w & 255) << 24);
    u32 p3 = (u32)(d.x & 255) | ((u32)(d.y & 255) << 8) | ((u32)(d.z & 255) << 16) | ((u32)(d.w & 255) << 24);
    reinterpret_cast<uint4*>(packed)[t] = make_uint4(p0, p1, p2, p3);
}

// k2: one plane per blockIdx.y; 16 px/thread: 16 packed bytes in -> 4x float4 out.
__global__ void __launch_bounds__(256) expand_kernel(
    const u32* __restrict__ packed, float* __restrict__ out, int total) {
    const u32 n = blockIdx.y;
    int t = blockIdx.x * 256 + threadIdx.x;
    long long i = (long long)t * 16;

    uint4 p = reinterpret_cast<const uint4*>(packed)[t];
    u32 w[4] = {p.x, p.y, p.z, p.w};
    float4* op = reinterpret_cast<float4*>(out + (long long)n * total + i);

#pragma unroll
    for (int k = 0; k < 4; ++k) {
        float4 v;
        v.x = (((w[k]      ) & 255u) == n) ? 1.0f : 0.0f;
        v.y = (((w[k] >> 8 ) & 255u) == n) ? 1.0f : 0.0f;
        v.z = (((w[k] >> 16) & 255u) == n) ? 1.0f : 0.0f;
        v.w = (((w[k] >> 24)       ) == n) ? 1.0f : 0.0f;
        op[k] = v;
    }
}

// Fallback (R1 structure) if N != 8 or ws too small.
__global__ void __launch_bounds__(256) get_one_hot_generic_kernel(
    const int* __restrict__ label, float* __restrict__ out,
    int total, int N) {
    long long i = ((long long)blockIdx.x * blockDim.x + threadIdx.x) * 4;
    if (i >= total) return;
    int4 lab = *reinterpret_cast<const int4*>(label + i);
    for (int n = 0; n < N; ++n) {
        float4 v;
        v.x = (lab.x == n) ? 1.0f : 0.0f;
        v.y = (lab.y == n) ? 1.0f : 0.0f;
        v.z = (lab.z == n) ? 1.0f : 0.0f;
        v.w = (lab.w == n) ? 1.0f : 0.0f;
        *reinterpret_cast<float4*>(out + (long long)n * total + i) = v;
    }
}

extern "C" void kernel_launch(void* const* d_in, const int* in_sizes, int n_in,
                              void* d_out, int out_size, void* d_ws, size_t ws_size,
                              hipStream_t stream) {
    const int* label = (const int*)d_in[0];
    float* out = (float*)d_out;

    int total = in_sizes[0];          // H*W = 16,777,216
    int N = out_size / total;         // 8

    bool fast = (N <= 256) && (total % 4096 == 0) && (ws_size >= (size_t)total);
    if (fast) {
        int blocks = total / 4096;    // 4096
        pack_labels_kernel<<<blocks, 256, 0, stream>>>(label, (u32*)d_ws, total);
        dim3 grid(blocks, N);         // 4096 x 8, x fastest -> plane-serial passes
        expand_kernel<<<grid, 256, 0, stream>>>((const u32*)d_ws, out, total);
    } else {
        int grid = (total / 4 + 255) / 256;
        get_one_hot_generic_kernel<<<grid, 256, 0, stream>>>(label, out, total, N);
    }
}

// Round 7
// 117.998 us; speedup vs baseline: 1.5641x; 1.5641x over previous
//
#include <hip/hip_runtime.h>
#include <hip/hip_bf16.h>

// One-hot: label (H*W int32) -> out (N, H, W) float32.
// Ideal traffic = 64 MiB read + 512 MiB write (~96 us at copy-class 6.3 TB/s).
//
// Journal:
//  R1 (8 plane-streams/thread, read-once):    130 us = 4.63 TB/s (8 concurrent 64MiB-apart write windows)
//  R3 (nontemporal stores):                   250 us (nt bypasses L2 write-combine -> partial-line RMW; never)
//  R4 (plane per blockIdx.y, 1 write window): 146 us (writes fast; 64MiB int32 label re-fetch thrashed L3)
//  R5 (wave-per-plane, staggered):            153 us (still 8 concurrent aliased windows)
//  R6 (pack->u8 + 16px/thread expand):        185 us (BROKE per-instruction coalescing: 4 float4/thread
//                                               at 64B lane stride = 4x write transactions @25% util.
//                                               LESSON: lane i -> base + i*16B, never per-thread chunks)
//
// R7 = R6 with coalescing fixed: k2 reads ONE packed u32 (4 labels) per lane
// (256B/wave) and writes ONE float4 per lane (1KiB/wave, lane-contiguous =
// R4's proven write pattern). Packed label = 16 MiB -> stays L3-resident
// across the 8 plane passes (R4's 64 MiB int32 didn't).

typedef unsigned int u32;

// k1: pack 16 labels/thread: 4x int4 in -> 16 bytes (uint4) out.
__global__ void __launch_bounds__(256) pack_labels_kernel(
    const int* __restrict__ label, u32* __restrict__ packed, int total) {
    int t = blockIdx.x * 256 + threadIdx.x;
    long long i = (long long)t * 16;
    if (i >= total) return;
    const int4* lp = reinterpret_cast<const int4*>(label + i);
    int4 a = lp[0], b = lp[1], c = lp[2], d = lp[3];
    u32 p0 = (u32)(a.x & 255) | ((u32)(a.y & 255) << 8) | ((u32)(a.z & 255) << 16) | ((u32)(a.w & 255) << 24);
    u32 p1 = (u32)(b.x & 255) | ((u32)(b.y & 255) << 8) | ((u32)(b.z & 255) << 16) | ((u32)(b.w & 255) << 24);
    u32 p2 = (u32)(c.x & 255) | ((u32)(c.y & 255) << 8) | ((u32)(c.z & 255) << 16) | ((u32)(c.w & 255) << 24);
    u32 p3 = (u32)(d.x & 255) | ((u32)(d.y & 255) << 8) | ((u32)(d.z & 255) << 16) | ((u32)(d.w & 255) << 24);
    reinterpret_cast<uint4*>(packed)[t] = make_uint4(p0, p1, p2, p3);
}

// k2: one plane per blockIdx.y; 4 px/thread.
// Lane reads 1 packed u32 (coalesced 256B/wave), writes 1 float4 at
// lane-contiguous addresses (coalesced 1KiB/wave).
__global__ void __launch_bounds__(256) expand_kernel(
    const u32* __restrict__ packed, float* __restrict__ out, int total) {
    const u32 n = blockIdx.y;
    int t = blockIdx.x * 256 + threadIdx.x;

    u32 w = packed[t];

    float4 v;
    v.x = (((w      ) & 255u) == n) ? 1.0f : 0.0f;
    v.y = (((w >> 8 ) & 255u) == n) ? 1.0f : 0.0f;
    v.z = (((w >> 16) & 255u) == n) ? 1.0f : 0.0f;
    v.w = (((w >> 24)       ) == n) ? 1.0f : 0.0f;

    *reinterpret_cast<float4*>(out + (long long)n * total + (long long)t * 4) = v;
}

// Fallback (R1 structure) if N != 8 or ws too small.
__global__ void __launch_bounds__(256) get_one_hot_generic_kernel(
    const int* __restrict__ label, float* __restrict__ out,
    int total, int N) {
    long long i = ((long long)blockIdx.x * blockDim.x + threadIdx.x) * 4;
    if (i >= total) return;
    int4 lab = *reinterpret_cast<const int4*>(label + i);
    for (int n = 0; n < N; ++n) {
        float4 v;
        v.x = (lab.x == n) ? 1.0f : 0.0f;
        v.y = (lab.y == n) ? 1.0f : 0.0f;
        v.z = (lab.z == n) ? 1.0f : 0.0f;
        v.w = (lab.w == n) ? 1.0f : 0.0f;
        *reinterpret_cast<float4*>(out + (long long)n * total + i) = v;
    }
}

extern "C" void kernel_launch(void* const* d_in, const int* in_sizes, int n_in,
                              void* d_out, int out_size, void* d_ws, size_t ws_size,
                              hipStream_t stream) {
    const int* label = (const int*)d_in[0];
    float* out = (float*)d_out;

    int total = in_sizes[0];          // H*W = 16,777,216
    int N = out_size / total;         // 8

    bool fast = (N <= 256) && (total % 4096 == 0) && (ws_size >= (size_t)total);
    if (fast) {
        pack_labels_kernel<<<total / 4096, 256, 0, stream>>>(label, (u32*)d_ws, total);
        dim3 grid(total / 1024, N);   // 16384 x 8; x fastest -> plane-serial passes
        expand_kernel<<<grid, 256, 0, stream>>>((const u32*)d_ws, out, total);
    } else {
        int grid = (total / 4 + 255) / 256;
        get_one_hot_generic_kernel<<<grid, 256, 0, stream>>>(label, out, total, N);
    }
}